// Round 20
// baseline (114.033 us; speedup 1.0000x reference)
//
#include <hip/hip_runtime.h>
#include <math.h>

#define NB 4        // batch
#define CIN 3       // IN_DIM
#define D0 6
#define D1 9
#define H1 256
#define W1 256
#define H2 64
#define W2 64
#define H3 16
#define W3 16
#define N1 (H1*W1)  // 65536
#define N2 (H2*W2)  // 4096
#define N3 (H3*W3)  // 256

#define SQRT3F 1.7320508075688772f
// razor width on UNSCALED lvl1 scores (= 1e-7 * sqrt(3); scores not divided)
#define EPS_BLEND_U 1.7320508075688772e-7

// ---- strict f32 ops (no FMA contraction) -------------------------------------
__device__ __forceinline__ float ADDF(float a, float b){ return __fadd_rn(a,b); }
__device__ __forceinline__ float SUBF(float a, float b){ return __fsub_rn(a,b); }
__device__ __forceinline__ float MULF(float a, float b){ return __fmul_rn(a,b); }
__device__ __forceinline__ float DIVF(float a, float b){ return __fdiv_rn(a,b); }

// ---------------- comparator: (score desc, index asc) strict total order ------
__device__ __forceinline__ bool better(double av, int ai, double bv, int bi) {
    return (av > bv) || (av == bv && ai < bi);
}
__device__ __forceinline__ void tk4(double s, int idx,
                                    double& v0, double& v1, double& v2, double& v3,
                                    int& j0, int& j1, int& j2, int& j3) {
    if (!better(s, idx, v3, j3)) return;
    if (better(s, idx, v0, j0))      { v3=v2;j3=j2; v2=v1;j2=j1; v1=v0;j1=j0; v0=s;j0=idx; }
    else if (better(s, idx, v1, j1)) { v3=v2;j3=j2; v2=v1;j2=j1; v1=s;j1=idx; }
    else if (better(s, idx, v2, j2)) { v3=v2;j3=j2; v2=s;j2=idx; }
    else                             { v3=s;j3=idx; }
}

// branchless compare-swap stage, FULL comparator (needed where exact ties occur:
// lvl2/lvl3 scores come from ReLU'd activations -> exact-zero ties are common)
#define TKSTAGE(vk, jk)                                                        \
    {                                                                          \
        bool bt = (s > (vk)) || ((s == (vk)) && (idx < (jk)));                 \
        double tv = bt ? (vk) : s;  int tj = bt ? (jk) : idx;                  \
        (vk) = bt ? s : (vk);       (jk) = bt ? idx : (jk);                    \
        s = tv; idx = tj;                                                      \
    }

// branchless compare-swap stage, STRICT > only. Valid at lvl1: raw gaussian
// input -> exact f64 score ties measure-zero; near-ties handled by value-based
// razor blend (insertion-order independent).
#define TKSTRICT(vk, jk)                                                       \
    {                                                                          \
        bool bt = (s > (vk));                                                  \
        double tv = bt ? (vk) : s;  int tj = bt ? (jk) : idx;                  \
        (vk) = bt ? s : (vk);       (jk) = bt ? idx : (jk);                    \
        s = tv; idx = tj;                                                      \
    }

// ---------------- conv 5x5 stride 4 pad 2, f32 rn -----------------------------
template<int CI, int CO, int HIN, int WIN, int HOUT, int WOUT>
__global__ void conv5x5_s4(const float* __restrict__ x, const float* __restrict__ w,
                           const float* __restrict__ bias, float* __restrict__ y) {
    int i = blockIdx.x * blockDim.x + threadIdx.x;
    if (i >= NB * CO * HOUT * WOUT) return;
    int ox = i % WOUT; int t = i / WOUT;
    int oy = t % HOUT; t /= HOUT;
    int o  = t % CO;   int b = t / CO;
    int iy0 = oy * 4 - 2, ix0 = ox * 4 - 2;
    float acc = 0.f;
    for (int c = 0; c < CI; ++c) {
        for (int ky = 0; ky < 5; ++ky) {
            int iy = iy0 + ky;
            if (iy < 0 || iy >= HIN) continue;
            for (int kx = 0; kx < 5; ++kx) {
                int ix = ix0 + kx;
                if (ix < 0 || ix >= WIN) continue;
                acc = ADDF(acc, MULF(w[((o*CI + c)*5 + ky)*5 + kx],
                                     x[((b*CI + c)*HIN + iy)*WIN + ix]));
            }
        }
    }
    y[i] = ADDF(acc, bias[o]);
}

// -------- bn_stats HW=4096, 1024 threads: all 4 batch leaves in parallel ------
template<int C>
__global__ void bn_stats_4096w(const float* __restrict__ xr, float* __restrict__ stats) {
    const int HW = 4096, NBLK = 32;
    __shared__ float chain[1024];      // [b][blk][c]
    __shared__ float bsArr[NB*NBLK];
    __shared__ float red[NB];
    __shared__ float mu_sh;
    int ch = blockIdx.x, t = threadIdx.x;    // blockDim = 1024
    int b = t >> 8, tt = t & 255, blk = tt >> 3, c = tt & 7;
    {
        const float* a = &xr[(b*C + ch)*HW + blk*128];
        float rc = a[c];
        #pragma unroll
        for (int i = 8; i < 128; i += 8) rc = ADDF(rc, a[i + c]);
        chain[t] = rc;
    }
    __syncthreads();
    if (tt < NBLK) {
        const float* r = &chain[b*256 + tt*8];
        bsArr[b*NBLK + tt] = ADDF(ADDF(ADDF(r[0],r[1]),ADDF(r[2],r[3])),
                                  ADDF(ADDF(r[4],r[5]),ADDF(r[6],r[7])));
    }
    __syncthreads();
    if (tt == 0) {
        float* bs = &bsArr[b*NBLK];
        int w = NBLK;
        while (w > 1) { for (int i2 = 0; i2 < (w>>1); ++i2) bs[i2] = ADDF(bs[2*i2], bs[2*i2+1]); w >>= 1; }
        red[b] = bs[0];
    }
    __syncthreads();
    if (t == 0) {
        float chan = red[0];
        for (int bb = 1; bb < NB; ++bb) chan = ADDF(chan, red[bb]);
        mu_sh = DIVF(chan, (float)(NB * HW));
    }
    __syncthreads();
    float mu = mu_sh;
    {
        const float* a = &xr[(b*C + ch)*HW + blk*128];
        float d = SUBF(a[c], mu);
        float rc = MULF(d, d);
        #pragma unroll
        for (int i = 8; i < 128; i += 8) { d = SUBF(a[i + c], mu); rc = ADDF(rc, MULF(d, d)); }
        chain[t] = rc;
    }
    __syncthreads();
    if (tt < NBLK) {
        const float* r = &chain[b*256 + tt*8];
        bsArr[b*NBLK + tt] = ADDF(ADDF(ADDF(r[0],r[1]),ADDF(r[2],r[3])),
                                  ADDF(ADDF(r[4],r[5]),ADDF(r[6],r[7])));
    }
    __syncthreads();
    if (tt == 0) {
        float* bs = &bsArr[b*NBLK];
        int w = NBLK;
        while (w > 1) { for (int i2 = 0; i2 < (w>>1); ++i2) bs[i2] = ADDF(bs[2*i2], bs[2*i2+1]); w >>= 1; }
        red[b] = bs[0];
    }
    __syncthreads();
    if (t == 0) {
        float chanv = red[0];
        for (int bb = 1; bb < NB; ++bb) chanv = ADDF(chanv, red[bb]);
        float var = DIVF(chanv, (float)(NB * HW));
        stats[ch*2+0] = mu_sh;
        stats[ch*2+1] = DIVF(1.0f, __fsqrt_rn(ADDF(var, 1e-5f)));
    }
}

// -------- bn_stats for HW=256 (2 leaf blocks): 16 parallel chains, 1 wave -----
template<int C>
__global__ void bn_stats_256(const float* __restrict__ xr, float* __restrict__ stats) {
    const int HW = 256, NBLK = 2;
    __shared__ float chain[16];
    __shared__ float bs[NBLK];
    __shared__ float mu_sh;
    int ch = blockIdx.x, t = threadIdx.x;   // blockDim = 64
    int blk = t >> 3, c = t & 7;
    float chan = 0.f;
    for (int b = 0; b < NB; ++b) {
        if (t < 16) {
            const float* a = &xr[(b*C + ch)*HW + blk*128];
            float rc = a[c];
            #pragma unroll
            for (int i = 8; i < 128; i += 8) rc = ADDF(rc, a[i + c]);
            chain[t] = rc;
        }
        __syncthreads();
        if (t < NBLK) {
            const float* r = &chain[t*8];
            bs[t] = ADDF(ADDF(ADDF(r[0],r[1]),ADDF(r[2],r[3])), ADDF(ADDF(r[4],r[5]),ADDF(r[6],r[7])));
        }
        __syncthreads();
        if (t == 0) {
            float s = ADDF(bs[0], bs[1]);
            chan = (b == 0) ? s : ADDF(chan, s);
        }
        __syncthreads();
    }
    if (t == 0) mu_sh = DIVF(chan, (float)(NB * HW));
    __syncthreads();
    float mu = mu_sh;
    float chanv = 0.f;
    for (int b = 0; b < NB; ++b) {
        if (t < 16) {
            const float* a = &xr[(b*C + ch)*HW + blk*128];
            float d = SUBF(a[c], mu);
            float rc = MULF(d, d);
            #pragma unroll
            for (int i = 8; i < 128; i += 8) { d = SUBF(a[i + c], mu); rc = ADDF(rc, MULF(d, d)); }
            chain[t] = rc;
        }
        __syncthreads();
        if (t < NBLK) {
            const float* r = &chain[t*8];
            bs[t] = ADDF(ADDF(ADDF(r[0],r[1]),ADDF(r[2],r[3])), ADDF(ADDF(r[4],r[5]),ADDF(r[6],r[7])));
        }
        __syncthreads();
        if (t == 0) {
            float s = ADDF(bs[0], bs[1]);
            chanv = (b == 0) ? s : ADDF(chanv, s);
        }
        __syncthreads();
    }
    if (t == 0) {
        float var = DIVF(chanv, (float)(NB * HW));
        stats[ch*2+0] = mu;
        stats[ch*2+1] = DIVF(1.0f, __fsqrt_rn(ADDF(var, 1e-5f)));
    }
}

// ---- fused bn_apply(x2r)->x2 AND k2 projection -------------------------------
__global__ void bnk2_k(const float* __restrict__ x2r, const float* __restrict__ stats,
                       const float* __restrict__ g, const float* __restrict__ beta,
                       const float* __restrict__ wk,
                       float* __restrict__ x2, float* __restrict__ k2) {
    int i = blockIdx.x * blockDim.x + threadIdx.x; // b*4096 + n
    if (i >= NB * N2) return;
    int b = i / N2, n = i % N2;
    float xv[D0];
    #pragma unroll
    for (int c = 0; c < D0; ++c) {
        float raw = x2r[(b*D0 + c)*N2 + n];
        float xn = MULF(SUBF(raw, stats[c*2]), stats[c*2+1]);
        float v = ADDF(MULF(xn, g[c]), beta[c]);
        v = v > 0.f ? v : 0.f;
        xv[c] = v;
        x2[(b*D0 + c)*N2 + n] = v;
    }
    #pragma unroll
    for (int o = 0; o < D0; ++o) {
        float ka = MULF(wk[o*D0], xv[0]);
        #pragma unroll
        for (int c = 1; c < D0; ++c) ka = ADDF(ka, MULF(wk[o*D0+c], xv[c]));
        k2[i*D0+o] = ka;
    }
}

// ---- fused bn_apply(x3r) + q3/k3 projections ---------------------------------
__global__ void qk3bn_k(const float* __restrict__ x3r, const float* __restrict__ stats,
                        const float* __restrict__ g, const float* __restrict__ beta,
                        const float* __restrict__ wq, const float* __restrict__ wk,
                        float* __restrict__ q3, float* __restrict__ k3) {
    int i = blockIdx.x * blockDim.x + threadIdx.x; // b*256 + n
    if (i >= NB * N3) return;
    int b = i / N3, n = i % N3;
    float xv[D1];
    #pragma unroll
    for (int c = 0; c < D1; ++c) {
        float raw = x3r[(b*D1 + c)*N3 + n];
        float xn = MULF(SUBF(raw, stats[c*2]), stats[c*2+1]);
        float v = ADDF(MULF(xn, g[c]), beta[c]);
        xv[c] = v > 0.f ? v : 0.f;
    }
    #pragma unroll
    for (int o = 0; o < D1; ++o) {
        float qa = MULF(wq[o*D1], xv[0]), ka = MULF(wk[o*D1], xv[0]);
        #pragma unroll
        for (int c = 1; c < D1; ++c) { qa = ADDF(qa, MULF(wq[o*D1+c], xv[c])); ka = ADDF(ka, MULF(wk[o*D1+c], xv[c])); }
        q3[i*D1+o] = qa; k3[i*D1+o] = ka;
    }
}

// level-3 selection: wave-per-query, f64 unscaled dots, ties -> lower.
__global__ void top3_w(const float* __restrict__ q3, const float* __restrict__ k3,
                       int* __restrict__ top3) {
    int bm = blockIdx.x;          // b*N3 + m
    int b  = bm >> 8;
    int lane = threadIdx.x;       // 0..63
    double qv[D1];
    #pragma unroll
    for (int o = 0; o < D1; ++o) qv[o] = (double)q3[bm*D1 + o];
    double v0=-INFINITY, v1=-INFINITY, v2=-INFINITY, v3=-INFINITY;
    int j0=0x7fffffff, j1=0x7fffffff, j2=0x7fffffff, j3=0x7fffffff;
    #pragma unroll
    for (int c = 0; c < 4; ++c) {
        int n = lane + c*64;
        const float* kr = &k3[(b*N3 + n)*D1];
        double s = 0.0;
        #pragma unroll
        for (int o = 0; o < D1; ++o) s += qv[o]*(double)kr[o];
        tk4(s, n, v0, v1, v2, v3, j0, j1, j2, j3);
    }
    for (int mask = 1; mask < 64; mask <<= 1) {
        double b0 = __shfl_xor(v0, mask), b1 = __shfl_xor(v1, mask);
        double b2 = __shfl_xor(v2, mask), b3 = __shfl_xor(v3, mask);
        int    c0 = __shfl_xor(j0, mask), c1 = __shfl_xor(j1, mask);
        int    c2 = __shfl_xor(j2, mask), c3 = __shfl_xor(j3, mask);
        tk4(b0, c0, v0, v1, v2, v3, j0, j1, j2, j3);
        tk4(b1, c1, v0, v1, v2, v3, j0, j1, j2, j3);
        tk4(b2, c2, v0, v1, v2, v3, j0, j1, j2, j3);
        tk4(b3, c3, v0, v1, v2, v3, j0, j1, j2, j3);
    }
    if (lane == 0) {
        top3[bm*4+0]=j0; top3[bm*4+1]=j1; top3[bm*4+2]=j2; top3[bm*4+3]=j3;
    }
}

// ---------------- level 2 selection (branchless top-4, f64 unscaled) ----------
__global__ void lvl2_t(const float* __restrict__ x2, const float* __restrict__ wq,
                       const float* __restrict__ k2, const int* __restrict__ top3,
                       int* __restrict__ top2) {
    int i = blockIdx.x * blockDim.x + threadIdx.x; // b*4096 + n
    if (i >= NB * N2) return;
    int b = i / N2, n = i % N2;
    int r = n / W2, cc = n % W2;
    int cell3 = (r >> 2) * W3 + (cc >> 2);
    double xv[D0];
    #pragma unroll
    for (int c = 0; c < D0; ++c) xv[c] = (double)x2[(b*D0 + c)*N2 + n];
    double qv[D0];
    #pragma unroll
    for (int o = 0; o < D0; ++o) {
        double qa = 0.0;
        #pragma unroll
        for (int c = 0; c < D0; ++c) qa += (double)wq[o*D0+c]*xv[c];
        qv[o] = qa;
    }
    double v0=-INFINITY, v1=-INFINITY, v2=-INFINITY, v3=-INFINITY;
    int j0=0x7fffffff, j1=0x7fffffff, j2=0x7fffffff, j3=0x7fffffff;
    const int* tp = &top3[(b*N3 + cell3)*4];
    for (int t = 0; t < 4; ++t) {
        int cell = tp[t];
        int R = cell / W3, C_ = cell % W3;
        int base = (R*4)*W2 + C_*4;
        #pragma unroll
        for (int dr = 0; dr < 4; ++dr) {
            int rowb = base + dr*W2;
            const float* kp = &k2[((long)b*N2 + rowb)*D0];  // 24 consecutive floats
            float4 f0 = *(const float4*)(kp +  0);
            float4 f1 = *(const float4*)(kp +  4);
            float4 f2 = *(const float4*)(kp +  8);
            float4 f3 = *(const float4*)(kp + 12);
            float4 f4 = *(const float4*)(kp + 16);
            float4 f5 = *(const float4*)(kp + 20);
            float k24[24];
            k24[0]=f0.x; k24[1]=f0.y; k24[2]=f0.z; k24[3]=f0.w;
            k24[4]=f1.x; k24[5]=f1.y; k24[6]=f1.z; k24[7]=f1.w;
            k24[8]=f2.x; k24[9]=f2.y; k24[10]=f2.z; k24[11]=f2.w;
            k24[12]=f3.x; k24[13]=f3.y; k24[14]=f3.z; k24[15]=f3.w;
            k24[16]=f4.x; k24[17]=f4.y; k24[18]=f4.z; k24[19]=f4.w;
            k24[20]=f5.x; k24[21]=f5.y; k24[22]=f5.z; k24[23]=f5.w;
            #pragma unroll
            for (int dc = 0; dc < 4; ++dc) {
                double s = 0.0;
                #pragma unroll
                for (int o = 0; o < D0; ++o) s += qv[o]*(double)k24[dc*D0+o];
                int idx = rowb + dc;
                TKSTAGE(v0, j0) TKSTAGE(v1, j1) TKSTAGE(v2, j2) TKSTAGE(v3, j3)
            }
        }
    }
    top2[i*4+0]=j0; top2[i*4+1]=j1; top2[i*4+2]=j2; top2[i*4+3]=j3;
}

// ------- level 1: dual-tracker ILP top-5 (strict insert), razor blend ---------
// Tracker A covers cells tp[0],tp[1]; tracker B covers tp[2],tp[3] — two
// independent compare-swap chains interleave in the pipeline. Merge with
// A-priority strict insert == single-tracker first-encounter tie behavior.
__global__ void lvl1_b(const float* __restrict__ x, const float* __restrict__ wq,
                       const float* __restrict__ wk, const int* __restrict__ top2,
                       float* __restrict__ out) {
    int i = blockIdx.x * blockDim.x + threadIdx.x; // b*65536 + n
    if (i >= NB * N1) return;
    int b = i >> 16, n = i & (N1 - 1);
    int r = n >> 8, cc = n & 255;
    int cell2 = (r >> 2) * W2 + (cc >> 2);
    const float* xb0 = x + (long)(b*CIN + 0)*N1;
    const float* xb1 = x + (long)(b*CIN + 1)*N1;
    const float* xb2 = x + (long)(b*CIN + 2)*N1;
    float x0 = xb0[n], x1 = xb1[n], x2_ = xb2[n];

    double q0d = (double)wq[0]*x0 + (double)wq[1]*x1 + (double)wq[2]*x2_;
    double q1d = (double)wq[3]*x0 + (double)wq[4]*x1 + (double)wq[5]*x2_;
    double q2d = (double)wq[6]*x0 + (double)wq[7]*x1 + (double)wq[8]*x2_;
    double p0 = (double)wk[0]*q0d + (double)wk[3]*q1d + (double)wk[6]*q2d;
    double p1 = (double)wk[1]*q0d + (double)wk[4]*q1d + (double)wk[7]*q2d;
    double p2 = (double)wk[2]*q0d + (double)wk[5]*q1d + (double)wk[8]*q2d;

    double va0=-INFINITY, va1=-INFINITY, va2=-INFINITY, va3=-INFINITY, va4=-INFINITY;
    int ja0=0x7fffffff, ja1=0x7fffffff, ja2=0x7fffffff, ja3=0x7fffffff, ja4=0x7fffffff;
    double vb0=-INFINITY, vb1=-INFINITY, vb2=-INFINITY, vb3=-INFINITY, vb4=-INFINITY;
    int jb0=0x7fffffff, jb1=0x7fffffff, jb2=0x7fffffff, jb3=0x7fffffff, jb4=0x7fffffff;

    const int* tp = &top2[(b*N2 + cell2)*4];
    #pragma unroll
    for (int t = 0; t < 2; ++t) {
        int cellA = tp[t];
        int cellB = tp[t + 2];
        int baseA = ((cellA >> 6)*4)*W1 + (cellA & 63)*4;
        int baseB = ((cellB >> 6)*4)*W1 + (cellB & 63)*4;
        #pragma unroll
        for (int dr = 0; dr < 4; ++dr) {
            int rowA = baseA + dr*W1;
            int rowB = baseB + dr*W1;
            float4 a0 = *(const float4*)(xb0 + rowA);
            float4 a1 = *(const float4*)(xb1 + rowA);
            float4 a2 = *(const float4*)(xb2 + rowA);
            float4 b0 = *(const float4*)(xb0 + rowB);
            float4 b1 = *(const float4*)(xb1 + rowB);
            float4 b2 = *(const float4*)(xb2 + rowB);
            float yA0[4] = {a0.x, a0.y, a0.z, a0.w};
            float yA1[4] = {a1.x, a1.y, a1.z, a1.w};
            float yA2[4] = {a2.x, a2.y, a2.z, a2.w};
            float yB0[4] = {b0.x, b0.y, b0.z, b0.w};
            float yB1[4] = {b1.x, b1.y, b1.z, b1.w};
            float yB2[4] = {b2.x, b2.y, b2.z, b2.w};
            #pragma unroll
            for (int dc = 0; dc < 4; ++dc) {
                double sA = p0*(double)yA0[dc] + p1*(double)yA1[dc] + p2*(double)yA2[dc];
                double sB = p0*(double)yB0[dc] + p1*(double)yB1[dc] + p2*(double)yB2[dc];
                { double s = sA; int idx = rowA + dc;
                  TKSTRICT(va0, ja0) TKSTRICT(va1, ja1) TKSTRICT(va2, ja2) TKSTRICT(va3, ja3) TKSTRICT(va4, ja4) }
                { double s = sB; int idx = rowB + dc;
                  TKSTRICT(vb0, jb0) TKSTRICT(vb1, jb1) TKSTRICT(vb2, jb2) TKSTRICT(vb3, jb3) TKSTRICT(vb4, jb4) }
            }
        }
    }
    // merge B (sorted desc) into A; strict > => A wins ties (first-encounter order)
    { double s = vb0; int idx = jb0;
      TKSTRICT(va0, ja0) TKSTRICT(va1, ja1) TKSTRICT(va2, ja2) TKSTRICT(va3, ja3) TKSTRICT(va4, ja4) }
    { double s = vb1; int idx = jb1;
      TKSTRICT(va0, ja0) TKSTRICT(va1, ja1) TKSTRICT(va2, ja2) TKSTRICT(va3, ja3) TKSTRICT(va4, ja4) }
    { double s = vb2; int idx = jb2;
      TKSTRICT(va0, ja0) TKSTRICT(va1, ja1) TKSTRICT(va2, ja2) TKSTRICT(va3, ja3) TKSTRICT(va4, ja4) }
    { double s = vb3; int idx = jb3;
      TKSTRICT(va0, ja0) TKSTRICT(va1, ja1) TKSTRICT(va2, ja2) TKSTRICT(va3, ja3) TKSTRICT(va4, ja4) }
    { double s = vb4; int idx = jb4;
      TKSTRICT(va0, ja0) TKSTRICT(va1, ja1) TKSTRICT(va2, ja2) TKSTRICT(va3, ja3) TKSTRICT(va4, ja4) }

    float q0 = MULF(wq[0],x0); q0 = ADDF(q0, MULF(wq[1],x1)); q0 = ADDF(q0, MULF(wq[2],x2_));
    float q1 = MULF(wq[3],x0); q1 = ADDF(q1, MULF(wq[4],x1)); q1 = ADDF(q1, MULF(wq[5],x2_));
    float q2 = MULF(wq[6],x0); q2 = ADDF(q2, MULF(wq[7],x1)); q2 = ADDF(q2, MULF(wq[8],x2_));
    auto kofY = [&](float y0, float y1, float y2, int o) -> float {
        float acc = MULF(wk[o*3+0], y0);
        acc = ADDF(acc, MULF(wk[o*3+1], y1));
        acc = ADDF(acc, MULF(wk[o*3+2], y2));
        return acc;
    };
    auto sofY = [&](float y0, float y1, float y2) -> float {
        float acc = MULF(q0, kofY(y0,y1,y2, 0));
        acc = ADDF(acc, MULF(q1, kofY(y0,y1,y2, 1)));
        acc = ADDF(acc, MULF(q2, kofY(y0,y1,y2, 2)));
        return DIVF(acc, SQRT3F);
    };
    auto emit = [&](int a0i, int a1i, int a2i, int a3i, float* o3) {
        float ya0 = xb0[a0i], ya1 = xb1[a0i], ya2 = xb2[a0i];
        float yb0 = xb0[a1i], yb1 = xb1[a1i], yb2 = xb2[a1i];
        float yc0 = xb0[a2i], yc1 = xb1[a2i], yc2 = xb2[a2i];
        float yd0 = xb0[a3i], yd1 = xb1[a3i], yd2 = xb2[a3i];
        float s0 = sofY(ya0,ya1,ya2), s1 = sofY(yb0,yb1,yb2);
        float s2 = sofY(yc0,yc1,yc2), s3 = sofY(yd0,yd1,yd2);
        float m4 = fmaxf(fmaxf(s0, s1), fmaxf(s2, s3));
        float e0 = expf(SUBF(s0, m4)), e1 = expf(SUBF(s1, m4));
        float e2 = expf(SUBF(s2, m4)), e3 = expf(SUBF(s3, m4));
        float S4 = ADDF(ADDF(ADDF(e0, e1), e2), e3);
        float w0 = DIVF(e0, S4), w1 = DIVF(e1, S4), w2 = DIVF(e2, S4), w3 = DIVF(e3, S4);
        for (int ch = 0; ch < CIN; ++ch) {
            float o_ch = MULF(w0, kofY(ya0,ya1,ya2, ch));
            o_ch = ADDF(o_ch, MULF(w1, kofY(yb0,yb1,yb2, ch)));
            o_ch = ADDF(o_ch, MULF(w2, kofY(yc0,yc1,yc2, ch)));
            o_ch = ADDF(o_ch, MULF(w3, kofY(yd0,yd1,yd2, ch)));
            o3[ch] = o_ch;
        }
    };

    float oA[CIN];
    emit(ja0, ja1, ja2, ja3, oA);
    bool razor = (va3 - va4) <= EPS_BLEND_U;   // includes exact ties
    if (razor && ja4 != 0x7fffffff) {
        float oB[CIN];
        emit(ja0, ja1, ja2, ja4, oB);
        for (int ch = 0; ch < CIN; ++ch)
            oA[ch] = 0.5f * (oA[ch] + oB[ch]);
    }
    for (int ch = 0; ch < CIN; ++ch)
        out[((long)(b*CIN + ch))*N1 + n] = oA[ch];
}

// ---------------- launch -------------------------------------------------------
extern "C" void kernel_launch(void* const* d_in, const int* in_sizes, int n_in,
                              void* d_out, int out_size, void* d_ws, size_t ws_size,
                              hipStream_t stream) {
    const float* x    = (const float*)d_in[0];
    const float* c1w  = (const float*)d_in[1];
    const float* c1b  = (const float*)d_in[2];
    const float* bn1g = (const float*)d_in[3];
    const float* bn1b = (const float*)d_in[4];
    const float* c2w  = (const float*)d_in[5];
    const float* c2b  = (const float*)d_in[6];
    const float* bn2g = (const float*)d_in[7];
    const float* bn2b = (const float*)d_in[8];
    const float* wq3  = (const float*)d_in[9];
    const float* wk3  = (const float*)d_in[10];
    const float* wq2  = (const float*)d_in[11];
    const float* wk2  = (const float*)d_in[12];
    const float* wq1  = (const float*)d_in[13];
    const float* wk1  = (const float*)d_in[14];
    float* out = (float*)d_out;

    float* ws   = (float*)d_ws;
    float* x2r  = ws;              // 98304
    float* x2   = x2r + NB*D0*N2;  // 98304
    float* x3r  = x2  + NB*D0*N2;  // 9216
    float* st1  = x3r + NB*D1*N3;  // 16
    float* st2  = st1 + 16;        // 32
    float* q3   = st2 + 32;        // 9216
    float* k3   = q3  + NB*N3*D1;  // 9216
    float* k2   = k3  + NB*N3*D1;  // 98304
    int*   top3 = (int*)(k2 + NB*N2*D0); // 4096 ints
    int*   top2 = top3 + NB*N3*4;        // 65536 ints

    conv5x5_s4<CIN, D0, H1, W1, H2, W2><<<768, 128, 0, stream>>>(x, c1w, c1b, x2r);
    bn_stats_4096w<D0><<<D0, 1024, 0, stream>>>(x2r, st1);
    bnk2_k<<<64, 256, 0, stream>>>(x2r, st1, bn1g, bn1b, wk2, x2, k2);

    conv5x5_s4<D0, D1, H2, W2, H3, W3><<<72, 128, 0, stream>>>(x2, c2w, c2b, x3r);
    bn_stats_256<D1><<<D1, 64, 0, stream>>>(x3r, st2);
    qk3bn_k<<<4, 256, 0, stream>>>(x3r, st2, bn2g, bn2b, wq3, wk3, q3, k3);

    top3_w<<<NB*N3, 64, 0, stream>>>(q3, k3, top3);

    lvl2_t<<<256, 64, 0, stream>>>(x2, wq2, k2, top3, top2);

    lvl1_b<<<2048, 128, 0, stream>>>(x, wq1, wk1, top2, out);
}

// Round 21
// 103.420 us; speedup vs baseline: 1.1026x; 1.1026x over previous
//
#include <hip/hip_runtime.h>
#include <math.h>

#define NB 4        // batch
#define CIN 3       // IN_DIM
#define D0 6
#define D1 9
#define H1 256
#define W1 256
#define H2 64
#define W2 64
#define H3 16
#define W3 16
#define N1 (H1*W1)  // 65536
#define N2 (H2*W2)  // 4096
#define N3 (H3*W3)  // 256

#define SQRT3F 1.7320508075688772f
// razor width on UNSCALED lvl1 scores (= 1e-7 * sqrt(3); scores not divided)
#define EPS_BLEND_U 1.7320508075688772e-7

// ---- strict f32 ops (no FMA contraction) -------------------------------------
__device__ __forceinline__ float ADDF(float a, float b){ return __fadd_rn(a,b); }
__device__ __forceinline__ float SUBF(float a, float b){ return __fsub_rn(a,b); }
__device__ __forceinline__ float MULF(float a, float b){ return __fmul_rn(a,b); }
__device__ __forceinline__ float DIVF(float a, float b){ return __fdiv_rn(a,b); }

// ---------------- comparator: (score desc, index asc) strict total order ------
// branchless compare-swap stage, FULL comparator (needed where exact ties occur:
// lvl2/lvl3 scores come from ReLU'd activations -> exact-zero ties are common)
#define TKSTAGE(vk, jk)                                                        \
    {                                                                          \
        bool bt = (s > (vk)) || ((s == (vk)) && (idx < (jk)));                 \
        double tv = bt ? (vk) : s;  int tj = bt ? (jk) : idx;                  \
        (vk) = bt ? s : (vk);       (jk) = bt ? idx : (jk);                    \
        s = tv; idx = tj;                                                      \
    }

// branchless compare-swap stage, STRICT > only. Valid at lvl1: raw gaussian
// input -> exact f64 score ties measure-zero; near-ties handled by value-based
// razor blend (insertion-order independent).
#define TKSTRICT(vk, jk)                                                       \
    {                                                                          \
        bool bt = (s > (vk));                                                  \
        double tv = bt ? (vk) : s;  int tj = bt ? (jk) : idx;                  \
        (vk) = bt ? s : (vk);       (jk) = bt ? idx : (jk);                    \
        s = tv; idx = tj;                                                      \
    }

// ---------------- conv 5x5 stride 4 pad 2, f32 rn -----------------------------
template<int CI, int CO, int HIN, int WIN, int HOUT, int WOUT>
__global__ void conv5x5_s4(const float* __restrict__ x, const float* __restrict__ w,
                           const float* __restrict__ bias, float* __restrict__ y) {
    int i = blockIdx.x * blockDim.x + threadIdx.x;
    if (i >= NB * CO * HOUT * WOUT) return;
    int ox = i % WOUT; int t = i / WOUT;
    int oy = t % HOUT; t /= HOUT;
    int o  = t % CO;   int b = t / CO;
    int iy0 = oy * 4 - 2, ix0 = ox * 4 - 2;
    float acc = 0.f;
    for (int c = 0; c < CI; ++c) {
        for (int ky = 0; ky < 5; ++ky) {
            int iy = iy0 + ky;
            if (iy < 0 || iy >= HIN) continue;
            for (int kx = 0; kx < 5; ++kx) {
                int ix = ix0 + kx;
                if (ix < 0 || ix >= WIN) continue;
                acc = ADDF(acc, MULF(w[((o*CI + c)*5 + ky)*5 + kx],
                                     x[((b*CI + c)*HIN + iy)*WIN + ix]));
            }
        }
    }
    y[i] = ADDF(acc, bias[o]);
}

// -------- bn_stats HW=4096, 1024 threads: all 4 batch leaves in parallel ------
template<int C>
__global__ void bn_stats_4096w(const float* __restrict__ xr, float* __restrict__ stats) {
    const int HW = 4096, NBLK = 32;
    __shared__ float chain[1024];      // [b][blk][c]
    __shared__ float bsArr[NB*NBLK];
    __shared__ float red[NB];
    __shared__ float mu_sh;
    int ch = blockIdx.x, t = threadIdx.x;    // blockDim = 1024
    int b = t >> 8, tt = t & 255, blk = tt >> 3, c = tt & 7;
    {
        const float* a = &xr[(b*C + ch)*HW + blk*128];
        float rc = a[c];
        #pragma unroll
        for (int i = 8; i < 128; i += 8) rc = ADDF(rc, a[i + c]);
        chain[t] = rc;
    }
    __syncthreads();
    if (tt < NBLK) {
        const float* r = &chain[b*256 + tt*8];
        bsArr[b*NBLK + tt] = ADDF(ADDF(ADDF(r[0],r[1]),ADDF(r[2],r[3])),
                                  ADDF(ADDF(r[4],r[5]),ADDF(r[6],r[7])));
    }
    __syncthreads();
    if (tt == 0) {
        float* bs = &bsArr[b*NBLK];
        int w = NBLK;
        while (w > 1) { for (int i2 = 0; i2 < (w>>1); ++i2) bs[i2] = ADDF(bs[2*i2], bs[2*i2+1]); w >>= 1; }
        red[b] = bs[0];
    }
    __syncthreads();
    if (t == 0) {
        float chan = red[0];
        for (int bb = 1; bb < NB; ++bb) chan = ADDF(chan, red[bb]);
        mu_sh = DIVF(chan, (float)(NB * HW));
    }
    __syncthreads();
    float mu = mu_sh;
    {
        const float* a = &xr[(b*C + ch)*HW + blk*128];
        float d = SUBF(a[c], mu);
        float rc = MULF(d, d);
        #pragma unroll
        for (int i = 8; i < 128; i += 8) { d = SUBF(a[i + c], mu); rc = ADDF(rc, MULF(d, d)); }
        chain[t] = rc;
    }
    __syncthreads();
    if (tt < NBLK) {
        const float* r = &chain[b*256 + tt*8];
        bsArr[b*NBLK + tt] = ADDF(ADDF(ADDF(r[0],r[1]),ADDF(r[2],r[3])),
                                  ADDF(ADDF(r[4],r[5]),ADDF(r[6],r[7])));
    }
    __syncthreads();
    if (tt == 0) {
        float* bs = &bsArr[b*NBLK];
        int w = NBLK;
        while (w > 1) { for (int i2 = 0; i2 < (w>>1); ++i2) bs[i2] = ADDF(bs[2*i2], bs[2*i2+1]); w >>= 1; }
        red[b] = bs[0];
    }
    __syncthreads();
    if (t == 0) {
        float chanv = red[0];
        for (int bb = 1; bb < NB; ++bb) chanv = ADDF(chanv, red[bb]);
        float var = DIVF(chanv, (float)(NB * HW));
        stats[ch*2+0] = mu_sh;
        stats[ch*2+1] = DIVF(1.0f, __fsqrt_rn(ADDF(var, 1e-5f)));
    }
}

// -------- bn_stats for HW=256 (2 leaf blocks): 16 parallel chains, 1 wave -----
template<int C>
__global__ void bn_stats_256(const float* __restrict__ xr, float* __restrict__ stats) {
    const int HW = 256, NBLK = 2;
    __shared__ float chain[16];
    __shared__ float bs[NBLK];
    __shared__ float mu_sh;
    int ch = blockIdx.x, t = threadIdx.x;   // blockDim = 64
    int blk = t >> 3, c = t & 7;
    float chan = 0.f;
    for (int b = 0; b < NB; ++b) {
        if (t < 16) {
            const float* a = &xr[(b*C + ch)*HW + blk*128];
            float rc = a[c];
            #pragma unroll
            for (int i = 8; i < 128; i += 8) rc = ADDF(rc, a[i + c]);
            chain[t] = rc;
        }
        __syncthreads();
        if (t < NBLK) {
            const float* r = &chain[t*8];
            bs[t] = ADDF(ADDF(ADDF(r[0],r[1]),ADDF(r[2],r[3])), ADDF(ADDF(r[4],r[5]),ADDF(r[6],r[7])));
        }
        __syncthreads();
        if (t == 0) {
            float s = ADDF(bs[0], bs[1]);
            chan = (b == 0) ? s : ADDF(chan, s);
        }
        __syncthreads();
    }
    if (t == 0) mu_sh = DIVF(chan, (float)(NB * HW));
    __syncthreads();
    float mu = mu_sh;
    float chanv = 0.f;
    for (int b = 0; b < NB; ++b) {
        if (t < 16) {
            const float* a = &xr[(b*C + ch)*HW + blk*128];
            float d = SUBF(a[c], mu);
            float rc = MULF(d, d);
            #pragma unroll
            for (int i = 8; i < 128; i += 8) { d = SUBF(a[i + c], mu); rc = ADDF(rc, MULF(d, d)); }
            chain[t] = rc;
        }
        __syncthreads();
        if (t < NBLK) {
            const float* r = &chain[t*8];
            bs[t] = ADDF(ADDF(ADDF(r[0],r[1]),ADDF(r[2],r[3])), ADDF(ADDF(r[4],r[5]),ADDF(r[6],r[7])));
        }
        __syncthreads();
        if (t == 0) {
            float s = ADDF(bs[0], bs[1]);
            chanv = (b == 0) ? s : ADDF(chanv, s);
        }
        __syncthreads();
    }
    if (t == 0) {
        float var = DIVF(chanv, (float)(NB * HW));
        stats[ch*2+0] = mu;
        stats[ch*2+1] = DIVF(1.0f, __fsqrt_rn(ADDF(var, 1e-5f)));
    }
}

// ---- fused bn_apply(x2r)->x2 AND k2 projection -------------------------------
__global__ void bnk2_k(const float* __restrict__ x2r, const float* __restrict__ stats,
                       const float* __restrict__ g, const float* __restrict__ beta,
                       const float* __restrict__ wk,
                       float* __restrict__ x2, float* __restrict__ k2) {
    int i = blockIdx.x * blockDim.x + threadIdx.x; // b*4096 + n
    if (i >= NB * N2) return;
    int b = i / N2, n = i % N2;
    float xv[D0];
    #pragma unroll
    for (int c = 0; c < D0; ++c) {
        float raw = x2r[(b*D0 + c)*N2 + n];
        float xn = MULF(SUBF(raw, stats[c*2]), stats[c*2+1]);
        float v = ADDF(MULF(xn, g[c]), beta[c]);
        v = v > 0.f ? v : 0.f;
        xv[c] = v;
        x2[(b*D0 + c)*N2 + n] = v;
    }
    #pragma unroll
    for (int o = 0; o < D0; ++o) {
        float ka = MULF(wk[o*D0], xv[0]);
        #pragma unroll
        for (int c = 1; c < D0; ++c) ka = ADDF(ka, MULF(wk[o*D0+c], xv[c]));
        k2[i*D0+o] = ka;
    }
}

// ---- fused bn_apply(x3r) + q3/k3 projections ---------------------------------
__global__ void qk3bn_k(const float* __restrict__ x3r, const float* __restrict__ stats,
                        const float* __restrict__ g, const float* __restrict__ beta,
                        const float* __restrict__ wq, const float* __restrict__ wk,
                        float* __restrict__ q3, float* __restrict__ k3) {
    int i = blockIdx.x * blockDim.x + threadIdx.x; // b*256 + n
    if (i >= NB * N3) return;
    int b = i / N3, n = i % N3;
    float xv[D1];
    #pragma unroll
    for (int c = 0; c < D1; ++c) {
        float raw = x3r[(b*D1 + c)*N3 + n];
        float xn = MULF(SUBF(raw, stats[c*2]), stats[c*2+1]);
        float v = ADDF(MULF(xn, g[c]), beta[c]);
        xv[c] = v > 0.f ? v : 0.f;
    }
    #pragma unroll
    for (int o = 0; o < D1; ++o) {
        float qa = MULF(wq[o*D1], xv[0]), ka = MULF(wk[o*D1], xv[0]);
        #pragma unroll
        for (int c = 1; c < D1; ++c) { qa = ADDF(qa, MULF(wq[o*D1+c], xv[c])); ka = ADDF(ka, MULF(wk[o*D1+c], xv[c])); }
        q3[i*D1+o] = qa; k3[i*D1+o] = ka;
    }
}

// level-3 selection: wave-per-query, f64 unscaled dots, ties -> lower.
// Branchless TKSTAGE everywhere (full comparator; cross-lane order unsorted).
__global__ void top3_w(const float* __restrict__ q3, const float* __restrict__ k3,
                       int* __restrict__ top3) {
    int bm = blockIdx.x;          // b*N3 + m
    int b  = bm >> 8;
    int lane = threadIdx.x;       // 0..63
    double qv[D1];
    #pragma unroll
    for (int o = 0; o < D1; ++o) qv[o] = (double)q3[bm*D1 + o];
    double v0=-INFINITY, v1=-INFINITY, v2=-INFINITY, v3=-INFINITY;
    int j0=0x7fffffff, j1=0x7fffffff, j2=0x7fffffff, j3=0x7fffffff;
    #pragma unroll
    for (int c = 0; c < 4; ++c) {
        int n = lane + c*64;
        const float* kr = &k3[(b*N3 + n)*D1];
        double sc = 0.0;
        #pragma unroll
        for (int o = 0; o < D1; ++o) sc += qv[o]*(double)kr[o];
        { double s = sc; int idx = n;
          TKSTAGE(v0, j0) TKSTAGE(v1, j1) TKSTAGE(v2, j2) TKSTAGE(v3, j3) }
    }
    for (int mask = 1; mask < 64; mask <<= 1) {
        double b0 = __shfl_xor(v0, mask), b1 = __shfl_xor(v1, mask);
        double b2 = __shfl_xor(v2, mask), b3 = __shfl_xor(v3, mask);
        int    c0 = __shfl_xor(j0, mask), c1 = __shfl_xor(j1, mask);
        int    c2 = __shfl_xor(j2, mask), c3 = __shfl_xor(j3, mask);
        { double s = b0; int idx = c0; TKSTAGE(v0,j0) TKSTAGE(v1,j1) TKSTAGE(v2,j2) TKSTAGE(v3,j3) }
        { double s = b1; int idx = c1; TKSTAGE(v0,j0) TKSTAGE(v1,j1) TKSTAGE(v2,j2) TKSTAGE(v3,j3) }
        { double s = b2; int idx = c2; TKSTAGE(v0,j0) TKSTAGE(v1,j1) TKSTAGE(v2,j2) TKSTAGE(v3,j3) }
        { double s = b3; int idx = c3; TKSTAGE(v0,j0) TKSTAGE(v1,j1) TKSTAGE(v2,j2) TKSTAGE(v3,j3) }
    }
    if (lane == 0) {
        top3[bm*4+0]=j0; top3[bm*4+1]=j1; top3[bm*4+2]=j2; top3[bm*4+3]=j3;
    }
}

// ---------------- level 2 selection (branchless top-4, f64 unscaled) ----------
__global__ void lvl2_t(const float* __restrict__ x2, const float* __restrict__ wq,
                       const float* __restrict__ k2, const int* __restrict__ top3,
                       int* __restrict__ top2) {
    int i = blockIdx.x * blockDim.x + threadIdx.x; // b*4096 + n
    if (i >= NB * N2) return;
    int b = i / N2, n = i % N2;
    int r = n / W2, cc = n % W2;
    int cell3 = (r >> 2) * W3 + (cc >> 2);
    double xv[D0];
    #pragma unroll
    for (int c = 0; c < D0; ++c) xv[c] = (double)x2[(b*D0 + c)*N2 + n];
    double qv[D0];
    #pragma unroll
    for (int o = 0; o < D0; ++o) {
        double qa = 0.0;
        #pragma unroll
        for (int c = 0; c < D0; ++c) qa += (double)wq[o*D0+c]*xv[c];
        qv[o] = qa;
    }
    double v0=-INFINITY, v1=-INFINITY, v2=-INFINITY, v3=-INFINITY;
    int j0=0x7fffffff, j1=0x7fffffff, j2=0x7fffffff, j3=0x7fffffff;
    const int* tp = &top3[(b*N3 + cell3)*4];
    for (int t = 0; t < 4; ++t) {
        int cell = tp[t];
        int R = cell / W3, C_ = cell % W3;
        int base = (R*4)*W2 + C_*4;
        #pragma unroll
        for (int dr = 0; dr < 4; ++dr) {
            int rowb = base + dr*W2;
            const float* kp = &k2[((long)b*N2 + rowb)*D0];  // 24 consecutive floats
            float4 f0 = *(const float4*)(kp +  0);
            float4 f1 = *(const float4*)(kp +  4);
            float4 f2 = *(const float4*)(kp +  8);
            float4 f3 = *(const float4*)(kp + 12);
            float4 f4 = *(const float4*)(kp + 16);
            float4 f5 = *(const float4*)(kp + 20);
            float k24[24];
            k24[0]=f0.x; k24[1]=f0.y; k24[2]=f0.z; k24[3]=f0.w;
            k24[4]=f1.x; k24[5]=f1.y; k24[6]=f1.z; k24[7]=f1.w;
            k24[8]=f2.x; k24[9]=f2.y; k24[10]=f2.z; k24[11]=f2.w;
            k24[12]=f3.x; k24[13]=f3.y; k24[14]=f3.z; k24[15]=f3.w;
            k24[16]=f4.x; k24[17]=f4.y; k24[18]=f4.z; k24[19]=f4.w;
            k24[20]=f5.x; k24[21]=f5.y; k24[22]=f5.z; k24[23]=f5.w;
            #pragma unroll
            for (int dc = 0; dc < 4; ++dc) {
                double s = 0.0;
                #pragma unroll
                for (int o = 0; o < D0; ++o) s += qv[o]*(double)k24[dc*D0+o];
                int idx = rowb + dc;
                TKSTAGE(v0, j0) TKSTAGE(v1, j1) TKSTAGE(v2, j2) TKSTAGE(v3, j3)
            }
        }
    }
    top2[i*4+0]=j0; top2[i*4+1]=j1; top2[i*4+2]=j2; top2[i*4+3]=j3;
}

// ------- level 1: full register preload, then pure-VALU top-5; razor blend ----
// Phase 1: all 48 float4 gathers issued back-to-back (independent, concurrent).
// Phase 2: selection in the same t/dr/dc order as before -> bit-identical.
__global__ void lvl1_b(const float* __restrict__ x, const float* __restrict__ wq,
                       const float* __restrict__ wk, const int* __restrict__ top2,
                       float* __restrict__ out) {
    int i = blockIdx.x * blockDim.x + threadIdx.x; // b*65536 + n
    if (i >= NB * N1) return;
    int b = i >> 16, n = i & (N1 - 1);
    int r = n >> 8, cc = n & 255;
    int cell2 = (r >> 2) * W2 + (cc >> 2);
    const float* xb0 = x + (long)(b*CIN + 0)*N1;
    const float* xb1 = x + (long)(b*CIN + 1)*N1;
    const float* xb2 = x + (long)(b*CIN + 2)*N1;
    float x0 = xb0[n], x1 = xb1[n], x2_ = xb2[n];

    double q0d = (double)wq[0]*x0 + (double)wq[1]*x1 + (double)wq[2]*x2_;
    double q1d = (double)wq[3]*x0 + (double)wq[4]*x1 + (double)wq[5]*x2_;
    double q2d = (double)wq[6]*x0 + (double)wq[7]*x1 + (double)wq[8]*x2_;
    double p0 = (double)wk[0]*q0d + (double)wk[3]*q1d + (double)wk[6]*q2d;
    double p1 = (double)wk[1]*q0d + (double)wk[4]*q1d + (double)wk[7]*q2d;
    double p2 = (double)wk[2]*q0d + (double)wk[5]*q1d + (double)wk[8]*q2d;

    const int* tp = &top2[(b*N2 + cell2)*4];
    // ---- phase 1: addresses + all 48 loads (static indexing -> registers) ----
    int rowb_[4][4];
    float4 Y0[4][4], Y1[4][4], Y2[4][4];
    #pragma unroll
    for (int t = 0; t < 4; ++t) {
        int cell = tp[t];
        int base = ((cell >> 6)*4)*W1 + (cell & 63)*4;
        #pragma unroll
        for (int dr = 0; dr < 4; ++dr) {
            int rowb = base + dr*W1;
            rowb_[t][dr] = rowb;
            Y0[t][dr] = *(const float4*)(xb0 + rowb);
            Y1[t][dr] = *(const float4*)(xb1 + rowb);
            Y2[t][dr] = *(const float4*)(xb2 + rowb);
        }
    }
    // ---- phase 2: pure-VALU selection (same order as before) -----------------
    double v0=-INFINITY, v1=-INFINITY, v2=-INFINITY, v3=-INFINITY, v4=-INFINITY;
    int j0=0x7fffffff, j1=0x7fffffff, j2=0x7fffffff, j3=0x7fffffff, j4=0x7fffffff;
    #pragma unroll
    for (int t = 0; t < 4; ++t) {
        #pragma unroll
        for (int dr = 0; dr < 4; ++dr) {
            int rowb = rowb_[t][dr];
            float y0v[4] = {Y0[t][dr].x, Y0[t][dr].y, Y0[t][dr].z, Y0[t][dr].w};
            float y1v[4] = {Y1[t][dr].x, Y1[t][dr].y, Y1[t][dr].z, Y1[t][dr].w};
            float y2v[4] = {Y2[t][dr].x, Y2[t][dr].y, Y2[t][dr].z, Y2[t][dr].w};
            #pragma unroll
            for (int dc = 0; dc < 4; ++dc) {
                double s = p0*(double)y0v[dc] + p1*(double)y1v[dc] + p2*(double)y2v[dc];
                int idx = rowb + dc;
                TKSTRICT(v0, j0) TKSTRICT(v1, j1) TKSTRICT(v2, j2) TKSTRICT(v3, j3) TKSTRICT(v4, j4)
            }
        }
    }

    float q0 = MULF(wq[0],x0); q0 = ADDF(q0, MULF(wq[1],x1)); q0 = ADDF(q0, MULF(wq[2],x2_));
    float q1 = MULF(wq[3],x0); q1 = ADDF(q1, MULF(wq[4],x1)); q1 = ADDF(q1, MULF(wq[5],x2_));
    float q2 = MULF(wq[6],x0); q2 = ADDF(q2, MULF(wq[7],x1)); q2 = ADDF(q2, MULF(wq[8],x2_));
    auto kofY = [&](float y0, float y1, float y2, int o) -> float {
        float acc = MULF(wk[o*3+0], y0);
        acc = ADDF(acc, MULF(wk[o*3+1], y1));
        acc = ADDF(acc, MULF(wk[o*3+2], y2));
        return acc;
    };
    auto sofY = [&](float y0, float y1, float y2) -> float {
        float acc = MULF(q0, kofY(y0,y1,y2, 0));
        acc = ADDF(acc, MULF(q1, kofY(y0,y1,y2, 1)));
        acc = ADDF(acc, MULF(q2, kofY(y0,y1,y2, 2)));
        return DIVF(acc, SQRT3F);
    };
    auto emit = [&](int a0i, int a1i, int a2i, int a3i, float* o3) {
        float ya0 = xb0[a0i], ya1 = xb1[a0i], ya2 = xb2[a0i];
        float yb0 = xb0[a1i], yb1 = xb1[a1i], yb2 = xb2[a1i];
        float yc0 = xb0[a2i], yc1 = xb1[a2i], yc2 = xb2[a2i];
        float yd0 = xb0[a3i], yd1 = xb1[a3i], yd2 = xb2[a3i];
        float s0 = sofY(ya0,ya1,ya2), s1 = sofY(yb0,yb1,yb2);
        float s2 = sofY(yc0,yc1,yc2), s3 = sofY(yd0,yd1,yd2);
        float m4 = fmaxf(fmaxf(s0, s1), fmaxf(s2, s3));
        float e0 = expf(SUBF(s0, m4)), e1 = expf(SUBF(s1, m4));
        float e2 = expf(SUBF(s2, m4)), e3 = expf(SUBF(s3, m4));
        float S4 = ADDF(ADDF(ADDF(e0, e1), e2), e3);
        float w0 = DIVF(e0, S4), w1 = DIVF(e1, S4), w2 = DIVF(e2, S4), w3 = DIVF(e3, S4);
        for (int ch = 0; ch < CIN; ++ch) {
            float o_ch = MULF(w0, kofY(ya0,ya1,ya2, ch));
            o_ch = ADDF(o_ch, MULF(w1, kofY(yb0,yb1,yb2, ch)));
            o_ch = ADDF(o_ch, MULF(w2, kofY(yc0,yc1,yc2, ch)));
            o_ch = ADDF(o_ch, MULF(w3, kofY(yd0,yd1,yd2, ch)));
            o3[ch] = o_ch;
        }
    };

    float oA[CIN];
    emit(j0, j1, j2, j3, oA);
    bool razor = (v3 - v4) <= EPS_BLEND_U;   // includes exact ties
    if (razor && j4 != 0x7fffffff) {
        float oB[CIN];
        emit(j0, j1, j2, j4, oB);
        for (int ch = 0; ch < CIN; ++ch)
            oA[ch] = 0.5f * (oA[ch] + oB[ch]);
    }
    for (int ch = 0; ch < CIN; ++ch)
        out[((long)(b*CIN + ch))*N1 + n] = oA[ch];
}

// ---------------- launch -------------------------------------------------------
extern "C" void kernel_launch(void* const* d_in, const int* in_sizes, int n_in,
                              void* d_out, int out_size, void* d_ws, size_t ws_size,
                              hipStream_t stream) {
    const float* x    = (const float*)d_in[0];
    const float* c1w  = (const float*)d_in[1];
    const float* c1b  = (const float*)d_in[2];
    const float* bn1g = (const float*)d_in[3];
    const float* bn1b = (const float*)d_in[4];
    const float* c2w  = (const float*)d_in[5];
    const float* c2b  = (const float*)d_in[6];
    const float* bn2g = (const float*)d_in[7];
    const float* bn2b = (const float*)d_in[8];
    const float* wq3  = (const float*)d_in[9];
    const float* wk3  = (const float*)d_in[10];
    const float* wq2  = (const float*)d_in[11];
    const float* wk2  = (const float*)d_in[12];
    const float* wq1  = (const float*)d_in[13];
    const float* wk1  = (const float*)d_in[14];
    float* out = (float*)d_out;

    float* ws   = (float*)d_ws;
    float* x2r  = ws;              // 98304
    float* x2   = x2r + NB*D0*N2;  // 98304
    float* x3r  = x2  + NB*D0*N2;  // 9216
    float* st1  = x3r + NB*D1*N3;  // 16
    float* st2  = st1 + 16;        // 32
    float* q3   = st2 + 32;        // 9216
    float* k3   = q3  + NB*N3*D1;  // 9216
    float* k2   = k3  + NB*N3*D1;  // 98304
    int*   top3 = (int*)(k2 + NB*N2*D0); // 4096 ints
    int*   top2 = top3 + NB*N3*4;        // 65536 ints

    conv5x5_s4<CIN, D0, H1, W1, H2, W2><<<768, 128, 0, stream>>>(x, c1w, c1b, x2r);
    bn_stats_4096w<D0><<<D0, 1024, 0, stream>>>(x2r, st1);
    bnk2_k<<<64, 256, 0, stream>>>(x2r, st1, bn1g, bn1b, wk2, x2, k2);

    conv5x5_s4<D0, D1, H2, W2, H3, W3><<<72, 128, 0, stream>>>(x2, c2w, c2b, x3r);
    bn_stats_256<D1><<<D1, 64, 0, stream>>>(x3r, st2);
    qk3bn_k<<<4, 256, 0, stream>>>(x3r, st2, bn2g, bn2b, wq3, wk3, q3, k3);

    top3_w<<<NB*N3, 64, 0, stream>>>(q3, k3, top3);

    lvl2_t<<<256, 64, 0, stream>>>(x2, wq2, k2, top3, top2);

    lvl1_b<<<2048, 128, 0, stream>>>(x, wq1, wk1, top2, out);
}

// Round 22
// 102.430 us; speedup vs baseline: 1.1133x; 1.0097x over previous
//
#include <hip/hip_runtime.h>
#include <math.h>

#define NB 4        // batch
#define CIN 3       // IN_DIM
#define D0 6
#define D1 9
#define H1 256
#define W1 256
#define H2 64
#define W2 64
#define H3 16
#define W3 16
#define N1 (H1*W1)  // 65536
#define N2 (H2*W2)  // 4096
#define N3 (H3*W3)  // 256

#define SQRT3F 1.7320508075688772f
// razor width on UNSCALED lvl1 scores (= 1e-7 * sqrt(3); scores not divided)
#define EPS_BLEND_U 1.7320508075688772e-7

// ---- strict f32 ops (no FMA contraction) -------------------------------------
__device__ __forceinline__ float ADDF(float a, float b){ return __fadd_rn(a,b); }
__device__ __forceinline__ float SUBF(float a, float b){ return __fsub_rn(a,b); }
__device__ __forceinline__ float MULF(float a, float b){ return __fmul_rn(a,b); }
__device__ __forceinline__ float DIVF(float a, float b){ return __fdiv_rn(a,b); }

// branchless compare-swap stage, FULL comparator (needed where exact ties occur:
// lvl2/lvl3 scores come from ReLU'd activations -> exact-zero ties are common)
#define TKSTAGE(vk, jk)                                                        \
    {                                                                          \
        bool bt = (s > (vk)) || ((s == (vk)) && (idx < (jk)));                 \
        double tv = bt ? (vk) : s;  int tj = bt ? (jk) : idx;                  \
        (vk) = bt ? s : (vk);       (jk) = bt ? idx : (jk);                    \
        s = tv; idx = tj;                                                      \
    }

// branchless compare-swap stage, STRICT > only (lvl1: exact ties measure-zero).
#define TKSTRICT(vk, jk)                                                       \
    {                                                                          \
        bool bt = (s > (vk));                                                  \
        double tv = bt ? (vk) : s;  int tj = bt ? (jk) : idx;                  \
        (vk) = bt ? s : (vk);       (jk) = bt ? idx : (jk);                    \
        s = tv; idx = tj;                                                      \
    }

// ---------------- conv 5x5 stride 4 pad 2, f32 rn -----------------------------
template<int CI, int CO, int HIN, int WIN, int HOUT, int WOUT>
__global__ void conv5x5_s4(const float* __restrict__ x, const float* __restrict__ w,
                           const float* __restrict__ bias, float* __restrict__ y) {
    int i = blockIdx.x * blockDim.x + threadIdx.x;
    if (i >= NB * CO * HOUT * WOUT) return;
    int ox = i % WOUT; int t = i / WOUT;
    int oy = t % HOUT; t /= HOUT;
    int o  = t % CO;   int b = t / CO;
    int iy0 = oy * 4 - 2, ix0 = ox * 4 - 2;
    float acc = 0.f;
    for (int c = 0; c < CI; ++c) {
        for (int ky = 0; ky < 5; ++ky) {
            int iy = iy0 + ky;
            if (iy < 0 || iy >= HIN) continue;
            for (int kx = 0; kx < 5; ++kx) {
                int ix = ix0 + kx;
                if (ix < 0 || ix >= WIN) continue;
                acc = ADDF(acc, MULF(w[((o*CI + c)*5 + ky)*5 + kx],
                                     x[((b*CI + c)*HIN + iy)*WIN + ix]));
            }
        }
    }
    y[i] = ADDF(acc, bias[o]);
}

// -------- bn_stats HW=4096, 1024 threads: all 4 batch leaves in parallel ------
template<int C>
__global__ void bn_stats_4096w(const float* __restrict__ xr, float* __restrict__ stats) {
    const int HW = 4096, NBLK = 32;
    __shared__ float chain[1024];      // [b][blk][c]
    __shared__ float bsArr[NB*NBLK];
    __shared__ float red[NB];
    __shared__ float mu_sh;
    int ch = blockIdx.x, t = threadIdx.x;    // blockDim = 1024
    int b = t >> 8, tt = t & 255, blk = tt >> 3, c = tt & 7;
    {
        const float* a = &xr[(b*C + ch)*HW + blk*128];
        float rc = a[c];
        #pragma unroll
        for (int i = 8; i < 128; i += 8) rc = ADDF(rc, a[i + c]);
        chain[t] = rc;
    }
    __syncthreads();
    if (tt < NBLK) {
        const float* r = &chain[b*256 + tt*8];
        bsArr[b*NBLK + tt] = ADDF(ADDF(ADDF(r[0],r[1]),ADDF(r[2],r[3])),
                                  ADDF(ADDF(r[4],r[5]),ADDF(r[6],r[7])));
    }
    __syncthreads();
    if (tt == 0) {
        float* bs = &bsArr[b*NBLK];
        int w = NBLK;
        while (w > 1) { for (int i2 = 0; i2 < (w>>1); ++i2) bs[i2] = ADDF(bs[2*i2], bs[2*i2+1]); w >>= 1; }
        red[b] = bs[0];
    }
    __syncthreads();
    if (t == 0) {
        float chan = red[0];
        for (int bb = 1; bb < NB; ++bb) chan = ADDF(chan, red[bb]);
        mu_sh = DIVF(chan, (float)(NB * HW));
    }
    __syncthreads();
    float mu = mu_sh;
    {
        const float* a = &xr[(b*C + ch)*HW + blk*128];
        float d = SUBF(a[c], mu);
        float rc = MULF(d, d);
        #pragma unroll
        for (int i = 8; i < 128; i += 8) { d = SUBF(a[i + c], mu); rc = ADDF(rc, MULF(d, d)); }
        chain[t] = rc;
    }
    __syncthreads();
    if (tt < NBLK) {
        const float* r = &chain[b*256 + tt*8];
        bsArr[b*NBLK + tt] = ADDF(ADDF(ADDF(r[0],r[1]),ADDF(r[2],r[3])),
                                  ADDF(ADDF(r[4],r[5]),ADDF(r[6],r[7])));
    }
    __syncthreads();
    if (tt == 0) {
        float* bs = &bsArr[b*NBLK];
        int w = NBLK;
        while (w > 1) { for (int i2 = 0; i2 < (w>>1); ++i2) bs[i2] = ADDF(bs[2*i2], bs[2*i2+1]); w >>= 1; }
        red[b] = bs[0];
    }
    __syncthreads();
    if (t == 0) {
        float chanv = red[0];
        for (int bb = 1; bb < NB; ++bb) chanv = ADDF(chanv, red[bb]);
        float var = DIVF(chanv, (float)(NB * HW));
        stats[ch*2+0] = mu_sh;
        stats[ch*2+1] = DIVF(1.0f, __fsqrt_rn(ADDF(var, 1e-5f)));
    }
}

// ---- fused bn_apply(x2r)->x2 AND k2 projection -------------------------------
__global__ void bnk2_k(const float* __restrict__ x2r, const float* __restrict__ stats,
                       const float* __restrict__ g, const float* __restrict__ beta,
                       const float* __restrict__ wk,
                       float* __restrict__ x2, float* __restrict__ k2) {
    int i = blockIdx.x * blockDim.x + threadIdx.x; // b*4096 + n
    if (i >= NB * N2) return;
    int b = i / N2, n = i % N2;
    float xv[D0];
    #pragma unroll
    for (int c = 0; c < D0; ++c) {
        float raw = x2r[(b*D0 + c)*N2 + n];
        float xn = MULF(SUBF(raw, stats[c*2]), stats[c*2+1]);
        float v = ADDF(MULF(xn, g[c]), beta[c]);
        v = v > 0.f ? v : 0.f;
        xv[c] = v;
        x2[(b*D0 + c)*N2 + n] = v;
    }
    #pragma unroll
    for (int o = 0; o < D0; ++o) {
        float ka = MULF(wk[o*D0], xv[0]);
        #pragma unroll
        for (int c = 1; c < D0; ++c) ka = ADDF(ka, MULF(wk[o*D0+c], xv[c]));
        k2[i*D0+o] = ka;
    }
}

// ---- FUSED: bn_stats(HW=256, all 9 channels) + bn_apply + q3/k3 projections --
// Single block of 1024 threads. Stats phase replicates bn_stats_256's exact
// ADDF DAG per channel (16 leaf chains, same combine tree, sequential over b);
// projection phase = qk3bn_k with stats from LDS. Bit-identical values.
__global__ void bnqk3_f(const float* __restrict__ x3r,
                        const float* __restrict__ g, const float* __restrict__ beta,
                        const float* __restrict__ wq, const float* __restrict__ wk,
                        float* __restrict__ q3, float* __restrict__ k3) {
    const int HW = N3;
    __shared__ float chain[D1*16];
    __shared__ float bsh[D1*2];
    __shared__ float acc_sh[D1];
    __shared__ float stats_sh[D1*2];
    int t = threadIdx.x;             // 0..1023
    int ch = t >> 4, blk = (t >> 3) & 1, c = t & 7;   // valid for t < 144
    // ---- mean ----
    for (int b = 0; b < NB; ++b) {
        if (t < D1*16) {
            const float* a = &x3r[(b*D1 + ch)*HW + blk*128];
            float rc = a[c];
            #pragma unroll
            for (int i = 8; i < 128; i += 8) rc = ADDF(rc, a[i + c]);
            chain[t] = rc;
        }
        __syncthreads();
        if (t < D1*2) {
            int chh = t >> 1, half = t & 1;
            const float* r = &chain[chh*16 + half*8];
            bsh[t] = ADDF(ADDF(ADDF(r[0],r[1]),ADDF(r[2],r[3])), ADDF(ADDF(r[4],r[5]),ADDF(r[6],r[7])));
        }
        __syncthreads();
        if (t < D1) {
            float s = ADDF(bsh[t*2], bsh[t*2+1]);
            acc_sh[t] = (b == 0) ? s : ADDF(acc_sh[t], s);
        }
        __syncthreads();
    }
    if (t < D1) stats_sh[t*2] = DIVF(acc_sh[t], (float)(NB * HW));
    __syncthreads();
    // ---- variance ----
    for (int b = 0; b < NB; ++b) {
        if (t < D1*16) {
            float mu = stats_sh[ch*2];
            const float* a = &x3r[(b*D1 + ch)*HW + blk*128];
            float d = SUBF(a[c], mu);
            float rc = MULF(d, d);
            #pragma unroll
            for (int i = 8; i < 128; i += 8) { d = SUBF(a[i + c], mu); rc = ADDF(rc, MULF(d, d)); }
            chain[t] = rc;
        }
        __syncthreads();
        if (t < D1*2) {
            int chh = t >> 1, half = t & 1;
            const float* r = &chain[chh*16 + half*8];
            bsh[t] = ADDF(ADDF(ADDF(r[0],r[1]),ADDF(r[2],r[3])), ADDF(ADDF(r[4],r[5]),ADDF(r[6],r[7])));
        }
        __syncthreads();
        if (t < D1) {
            float s = ADDF(bsh[t*2], bsh[t*2+1]);
            acc_sh[t] = (b == 0) ? s : ADDF(acc_sh[t], s);
        }
        __syncthreads();
    }
    if (t < D1) {
        float var = DIVF(acc_sh[t], (float)(NB * HW));
        stats_sh[t*2+1] = DIVF(1.0f, __fsqrt_rn(ADDF(var, 1e-5f)));
    }
    __syncthreads();
    // ---- projection phase: i = t = b*256 + n ----
    {
        int i = t;
        int b = i / N3, n = i % N3;
        float xv[D1];
        #pragma unroll
        for (int cc = 0; cc < D1; ++cc) {
            float raw = x3r[(b*D1 + cc)*N3 + n];
            float xn = MULF(SUBF(raw, stats_sh[cc*2]), stats_sh[cc*2+1]);
            float v = ADDF(MULF(xn, g[cc]), beta[cc]);
            xv[cc] = v > 0.f ? v : 0.f;
        }
        #pragma unroll
        for (int o = 0; o < D1; ++o) {
            float qa = MULF(wq[o*D1], xv[0]), ka = MULF(wk[o*D1], xv[0]);
            #pragma unroll
            for (int cc = 1; cc < D1; ++cc) { qa = ADDF(qa, MULF(wq[o*D1+cc], xv[cc])); ka = ADDF(ka, MULF(wk[o*D1+cc], xv[cc])); }
            q3[i*D1+o] = qa; k3[i*D1+o] = ka;
        }
    }
}

// level-3 selection: wave-per-query, f64 unscaled dots, ties -> lower.
__global__ void top3_w(const float* __restrict__ q3, const float* __restrict__ k3,
                       int* __restrict__ top3) {
    int bm = blockIdx.x;          // b*N3 + m
    int b  = bm >> 8;
    int lane = threadIdx.x;       // 0..63
    double qv[D1];
    #pragma unroll
    for (int o = 0; o < D1; ++o) qv[o] = (double)q3[bm*D1 + o];
    double v0=-INFINITY, v1=-INFINITY, v2=-INFINITY, v3=-INFINITY;
    int j0=0x7fffffff, j1=0x7fffffff, j2=0x7fffffff, j3=0x7fffffff;
    #pragma unroll
    for (int c = 0; c < 4; ++c) {
        int n = lane + c*64;
        const float* kr = &k3[(b*N3 + n)*D1];
        double sc = 0.0;
        #pragma unroll
        for (int o = 0; o < D1; ++o) sc += qv[o]*(double)kr[o];
        { double s = sc; int idx = n;
          TKSTAGE(v0, j0) TKSTAGE(v1, j1) TKSTAGE(v2, j2) TKSTAGE(v3, j3) }
    }
    for (int mask = 1; mask < 64; mask <<= 1) {
        double b0 = __shfl_xor(v0, mask), b1 = __shfl_xor(v1, mask);
        double b2 = __shfl_xor(v2, mask), b3 = __shfl_xor(v3, mask);
        int    c0 = __shfl_xor(j0, mask), c1 = __shfl_xor(j1, mask);
        int    c2 = __shfl_xor(j2, mask), c3 = __shfl_xor(j3, mask);
        { double s = b0; int idx = c0; TKSTAGE(v0,j0) TKSTAGE(v1,j1) TKSTAGE(v2,j2) TKSTAGE(v3,j3) }
        { double s = b1; int idx = c1; TKSTAGE(v0,j0) TKSTAGE(v1,j1) TKSTAGE(v2,j2) TKSTAGE(v3,j3) }
        { double s = b2; int idx = c2; TKSTAGE(v0,j0) TKSTAGE(v1,j1) TKSTAGE(v2,j2) TKSTAGE(v3,j3) }
        { double s = b3; int idx = c3; TKSTAGE(v0,j0) TKSTAGE(v1,j1) TKSTAGE(v2,j2) TKSTAGE(v3,j3) }
    }
    if (lane == 0) {
        top3[bm*4+0]=j0; top3[bm*4+1]=j1; top3[bm*4+2]=j2; top3[bm*4+3]=j3;
    }
}

// ---- level 2 selection: per-cell preload (24 float4) then pure-VALU ----------
__global__ void lvl2_t(const float* __restrict__ x2, const float* __restrict__ wq,
                       const float* __restrict__ k2, const int* __restrict__ top3,
                       int* __restrict__ top2) {
    int i = blockIdx.x * blockDim.x + threadIdx.x; // b*4096 + n
    if (i >= NB * N2) return;
    int b = i / N2, n = i % N2;
    int r = n / W2, cc = n % W2;
    int cell3 = (r >> 2) * W3 + (cc >> 2);
    double xv[D0];
    #pragma unroll
    for (int c = 0; c < D0; ++c) xv[c] = (double)x2[(b*D0 + c)*N2 + n];
    double qv[D0];
    #pragma unroll
    for (int o = 0; o < D0; ++o) {
        double qa = 0.0;
        #pragma unroll
        for (int c = 0; c < D0; ++c) qa += (double)wq[o*D0+c]*xv[c];
        qv[o] = qa;
    }
    double v0=-INFINITY, v1=-INFINITY, v2=-INFINITY, v3=-INFINITY;
    int j0=0x7fffffff, j1=0x7fffffff, j2=0x7fffffff, j3=0x7fffffff;
    const int* tp = &top3[(b*N3 + cell3)*4];
    for (int t = 0; t < 4; ++t) {
        int cell = tp[t];
        int R = cell / W3, C_ = cell % W3;
        int base = (R*4)*W2 + C_*4;
        // phase 1: preload the cell's 24 float4 (all independent, in flight)
        float4 F[4][6];
        int rowbs[4];
        #pragma unroll
        for (int dr = 0; dr < 4; ++dr) {
            int rowb = base + dr*W2;
            rowbs[dr] = rowb;
            const float* kp = &k2[((long)b*N2 + rowb)*D0];
            F[dr][0] = *(const float4*)(kp +  0);
            F[dr][1] = *(const float4*)(kp +  4);
            F[dr][2] = *(const float4*)(kp +  8);
            F[dr][3] = *(const float4*)(kp + 12);
            F[dr][4] = *(const float4*)(kp + 16);
            F[dr][5] = *(const float4*)(kp + 20);
        }
        // phase 2: same dr/dc order as before -> bit-identical
        #pragma unroll
        for (int dr = 0; dr < 4; ++dr) {
            float k24[24];
            k24[0]=F[dr][0].x; k24[1]=F[dr][0].y; k24[2]=F[dr][0].z; k24[3]=F[dr][0].w;
            k24[4]=F[dr][1].x; k24[5]=F[dr][1].y; k24[6]=F[dr][1].z; k24[7]=F[dr][1].w;
            k24[8]=F[dr][2].x; k24[9]=F[dr][2].y; k24[10]=F[dr][2].z; k24[11]=F[dr][2].w;
            k24[12]=F[dr][3].x; k24[13]=F[dr][3].y; k24[14]=F[dr][3].z; k24[15]=F[dr][3].w;
            k24[16]=F[dr][4].x; k24[17]=F[dr][4].y; k24[18]=F[dr][4].z; k24[19]=F[dr][4].w;
            k24[20]=F[dr][5].x; k24[21]=F[dr][5].y; k24[22]=F[dr][5].z; k24[23]=F[dr][5].w;
            int rowb = rowbs[dr];
            #pragma unroll
            for (int dc = 0; dc < 4; ++dc) {
                double s = 0.0;
                #pragma unroll
                for (int o = 0; o < D0; ++o) s += qv[o]*(double)k24[dc*D0+o];
                int idx = rowb + dc;
                TKSTAGE(v0, j0) TKSTAGE(v1, j1) TKSTAGE(v2, j2) TKSTAGE(v3, j3)
            }
        }
    }
    top2[i*4+0]=j0; top2[i*4+1]=j1; top2[i*4+2]=j2; top2[i*4+3]=j3;
}

// ------- level 1: full register preload, then pure-VALU top-5; razor blend ----
__global__ void lvl1_b(const float* __restrict__ x, const float* __restrict__ wq,
                       const float* __restrict__ wk, const int* __restrict__ top2,
                       float* __restrict__ out) {
    int i = blockIdx.x * blockDim.x + threadIdx.x; // b*65536 + n
    if (i >= NB * N1) return;
    int b = i >> 16, n = i & (N1 - 1);
    int r = n >> 8, cc = n & 255;
    int cell2 = (r >> 2) * W2 + (cc >> 2);
    const float* xb0 = x + (long)(b*CIN + 0)*N1;
    const float* xb1 = x + (long)(b*CIN + 1)*N1;
    const float* xb2 = x + (long)(b*CIN + 2)*N1;
    float x0 = xb0[n], x1 = xb1[n], x2_ = xb2[n];

    double q0d = (double)wq[0]*x0 + (double)wq[1]*x1 + (double)wq[2]*x2_;
    double q1d = (double)wq[3]*x0 + (double)wq[4]*x1 + (double)wq[5]*x2_;
    double q2d = (double)wq[6]*x0 + (double)wq[7]*x1 + (double)wq[8]*x2_;
    double p0 = (double)wk[0]*q0d + (double)wk[3]*q1d + (double)wk[6]*q2d;
    double p1 = (double)wk[1]*q0d + (double)wk[4]*q1d + (double)wk[7]*q2d;
    double p2 = (double)wk[2]*q0d + (double)wk[5]*q1d + (double)wk[8]*q2d;

    const int* tp = &top2[(b*N2 + cell2)*4];
    int rowb_[4][4];
    float4 Y0[4][4], Y1[4][4], Y2[4][4];
    #pragma unroll
    for (int t = 0; t < 4; ++t) {
        int cell = tp[t];
        int base = ((cell >> 6)*4)*W1 + (cell & 63)*4;
        #pragma unroll
        for (int dr = 0; dr < 4; ++dr) {
            int rowb = base + dr*W1;
            rowb_[t][dr] = rowb;
            Y0[t][dr] = *(const float4*)(xb0 + rowb);
            Y1[t][dr] = *(const float4*)(xb1 + rowb);
            Y2[t][dr] = *(const float4*)(xb2 + rowb);
        }
    }
    double v0=-INFINITY, v1=-INFINITY, v2=-INFINITY, v3=-INFINITY, v4=-INFINITY;
    int j0=0x7fffffff, j1=0x7fffffff, j2=0x7fffffff, j3=0x7fffffff, j4=0x7fffffff;
    #pragma unroll
    for (int t = 0; t < 4; ++t) {
        #pragma unroll
        for (int dr = 0; dr < 4; ++dr) {
            int rowb = rowb_[t][dr];
            float y0v[4] = {Y0[t][dr].x, Y0[t][dr].y, Y0[t][dr].z, Y0[t][dr].w};
            float y1v[4] = {Y1[t][dr].x, Y1[t][dr].y, Y1[t][dr].z, Y1[t][dr].w};
            float y2v[4] = {Y2[t][dr].x, Y2[t][dr].y, Y2[t][dr].z, Y2[t][dr].w};
            #pragma unroll
            for (int dc = 0; dc < 4; ++dc) {
                double s = p0*(double)y0v[dc] + p1*(double)y1v[dc] + p2*(double)y2v[dc];
                int idx = rowb + dc;
                TKSTRICT(v0, j0) TKSTRICT(v1, j1) TKSTRICT(v2, j2) TKSTRICT(v3, j3) TKSTRICT(v4, j4)
            }
        }
    }

    float q0 = MULF(wq[0],x0); q0 = ADDF(q0, MULF(wq[1],x1)); q0 = ADDF(q0, MULF(wq[2],x2_));
    float q1 = MULF(wq[3],x0); q1 = ADDF(q1, MULF(wq[4],x1)); q1 = ADDF(q1, MULF(wq[5],x2_));
    float q2 = MULF(wq[6],x0); q2 = ADDF(q2, MULF(wq[7],x1)); q2 = ADDF(q2, MULF(wq[8],x2_));
    auto kofY = [&](float y0, float y1, float y2, int o) -> float {
        float acc = MULF(wk[o*3+0], y0);
        acc = ADDF(acc, MULF(wk[o*3+1], y1));
        acc = ADDF(acc, MULF(wk[o*3+2], y2));
        return acc;
    };
    auto sofY = [&](float y0, float y1, float y2) -> float {
        float acc = MULF(q0, kofY(y0,y1,y2, 0));
        acc = ADDF(acc, MULF(q1, kofY(y0,y1,y2, 1)));
        acc = ADDF(acc, MULF(q2, kofY(y0,y1,y2, 2)));
        return DIVF(acc, SQRT3F);
    };
    auto emit = [&](int a0i, int a1i, int a2i, int a3i, float* o3) {
        float ya0 = xb0[a0i], ya1 = xb1[a0i], ya2 = xb2[a0i];
        float yb0 = xb0[a1i], yb1 = xb1[a1i], yb2 = xb2[a1i];
        float yc0 = xb0[a2i], yc1 = xb1[a2i], yc2 = xb2[a2i];
        float yd0 = xb0[a3i], yd1 = xb1[a3i], yd2 = xb2[a3i];
        float s0 = sofY(ya0,ya1,ya2), s1 = sofY(yb0,yb1,yb2);
        float s2 = sofY(yc0,yc1,yc2), s3 = sofY(yd0,yd1,yd2);
        float m4 = fmaxf(fmaxf(s0, s1), fmaxf(s2, s3));
        float e0 = expf(SUBF(s0, m4)), e1 = expf(SUBF(s1, m4));
        float e2 = expf(SUBF(s2, m4)), e3 = expf(SUBF(s3, m4));
        float S4 = ADDF(ADDF(ADDF(e0, e1), e2), e3);
        float w0 = DIVF(e0, S4), w1 = DIVF(e1, S4), w2 = DIVF(e2, S4), w3 = DIVF(e3, S4);
        for (int ch = 0; ch < CIN; ++ch) {
            float o_ch = MULF(w0, kofY(ya0,ya1,ya2, ch));
            o_ch = ADDF(o_ch, MULF(w1, kofY(yb0,yb1,yb2, ch)));
            o_ch = ADDF(o_ch, MULF(w2, kofY(yc0,yc1,yc2, ch)));
            o_ch = ADDF(o_ch, MULF(w3, kofY(yd0,yd1,yd2, ch)));
            o3[ch] = o_ch;
        }
    };

    float oA[CIN];
    emit(j0, j1, j2, j3, oA);
    bool razor = (v3 - v4) <= EPS_BLEND_U;   // includes exact ties
    if (razor && j4 != 0x7fffffff) {
        float oB[CIN];
        emit(j0, j1, j2, j4, oB);
        for (int ch = 0; ch < CIN; ++ch)
            oA[ch] = 0.5f * (oA[ch] + oB[ch]);
    }
    for (int ch = 0; ch < CIN; ++ch)
        out[((long)(b*CIN + ch))*N1 + n] = oA[ch];
}

// ---------------- launch -------------------------------------------------------
extern "C" void kernel_launch(void* const* d_in, const int* in_sizes, int n_in,
                              void* d_out, int out_size, void* d_ws, size_t ws_size,
                              hipStream_t stream) {
    const float* x    = (const float*)d_in[0];
    const float* c1w  = (const float*)d_in[1];
    const float* c1b  = (const float*)d_in[2];
    const float* bn1g = (const float*)d_in[3];
    const float* bn1b = (const float*)d_in[4];
    const float* c2w  = (const float*)d_in[5];
    const float* c2b  = (const float*)d_in[6];
    const float* bn2g = (const float*)d_in[7];
    const float* bn2b = (const float*)d_in[8];
    const float* wq3  = (const float*)d_in[9];
    const float* wk3  = (const float*)d_in[10];
    const float* wq2  = (const float*)d_in[11];
    const float* wk2  = (const float*)d_in[12];
    const float* wq1  = (const float*)d_in[13];
    const float* wk1  = (const float*)d_in[14];
    float* out = (float*)d_out;

    float* ws   = (float*)d_ws;
    float* x2r  = ws;              // 98304
    float* x2   = x2r + NB*D0*N2;  // 98304
    float* x3r  = x2  + NB*D0*N2;  // 9216
    float* st1  = x3r + NB*D1*N3;  // 16
    float* st2  = st1 + 16;        // 32 (unused now)
    float* q3   = st2 + 32;        // 9216
    float* k3   = q3  + NB*N3*D1;  // 9216
    float* k2   = k3  + NB*N3*D1;  // 98304
    int*   top3 = (int*)(k2 + NB*N2*D0); // 4096 ints
    int*   top2 = top3 + NB*N3*4;        // 65536 ints

    conv5x5_s4<CIN, D0, H1, W1, H2, W2><<<768, 128, 0, stream>>>(x, c1w, c1b, x2r);
    bn_stats_4096w<D0><<<D0, 1024, 0, stream>>>(x2r, st1);
    bnk2_k<<<64, 256, 0, stream>>>(x2r, st1, bn1g, bn1b, wk2, x2, k2);

    conv5x5_s4<D0, D1, H2, W2, H3, W3><<<72, 128, 0, stream>>>(x2, c2w, c2b, x3r);
    bnqk3_f<<<1, 1024, 0, stream>>>(x3r, bn2g, bn2b, wq3, wk3, q3, k3);

    top3_w<<<NB*N3, 64, 0, stream>>>(q3, k3, top3);

    lvl2_t<<<256, 64, 0, stream>>>(x2, wq2, k2, top3, top2);

    lvl1_b<<<2048, 128, 0, stream>>>(x, wq1, wk1, top2, out);
}